// Round 22
// baseline (365.920 us; speedup 1.0000x reference)
//
#include <hip/hip_runtime.h>

// ---------------------------------------------------------------------------
// multihead_attention_87454124081549 — round 22
// Round-22 (from r21 best, 281us): k_denom __launch_bounds__(256,5) — LDS is
// already exactly 32KB (5 blocks/CU eligible) but VGPR=104 capped it at 4
// waves/SIMD (512/104). Forcing <=102 VGPR unlocks the 5th block, matching
// the r21 k_attn occupancy win. All else byte-identical to round 21.
// JOURNAL: exp2-fold of dinv FAILED twice (r8/r9); r12/r13/r19 restructures
// net-negative; r11 prefetch neutral; r18 dinv rotation is load-bearing.
// Trail: 804->537->531->517->456->389->343->335->330->322->306->293->288->284->281.
// ---------------------------------------------------------------------------

typedef __attribute__((ext_vector_type(4))) float f32x4;
typedef __attribute__((ext_vector_type(8))) short bf16x8;

#define LOG2E 1.4426950408889634f
#define SM_SCALE (1.4426950408889634f / 5.656854249492381f)  // log2(e)/sqrt(32)

#define CVT_PK(d, lo, hi) \
    asm("v_cvt_pk_bf16_f32 %0, %1, %2" : "=v"(d) : "v"(lo), "v"(hi))
#define SWAP32(x, y) \
    asm("v_permlane32_swap_b32 %0, %1" : "+v"(x), "+v"(y))
#define SWAP16(x, y) \
    asm("v_permlane16_swap_b32 %0, %1" : "+v"(x), "+v"(y))
#define GLOAD16(g, p) __builtin_amdgcn_global_load_lds( \
    (const __attribute__((address_space(1))) void*)(g), \
    (__attribute__((address_space(3))) void*)(p), 16, 0, 0)

__device__ __forceinline__ unsigned short f2bf(float x) {
    union { float f; unsigned u; } v; v.f = x;
    unsigned r = v.u + 0x7FFFu + ((v.u >> 16) & 1u);   // RNE
    return (unsigned short)(r >> 16);
}

__device__ __forceinline__ float bf2f(unsigned short x) {
    union { unsigned u; float f; } v; v.u = ((unsigned)x) << 16;
    return v.f;
}

__device__ __forceinline__ float fast_tanh(float x) {
    float e = __builtin_amdgcn_exp2f(x * (2.0f * LOG2E));   // exp(2x)
    return 1.0f - 2.0f * __builtin_amdgcn_rcpf(e + 1.0f);
}

__device__ __forceinline__ f32x4 mfma_bf16(bf16x8 a, bf16x8 b, f32x4 c) {
    return __builtin_amdgcn_mfma_f32_16x16x32_bf16(a, b, c, 0, 0, 0);
}

// ---------------------------------------------------------------------------
// Weight conversion: 7 x (256x256) + W5 (256x1024) fp32 -> bf16, concatenated.
// Order: WQ(0) WV(1) WQ3(2) WK3(3) WV3(4) WQ4(5) WV4(6) W5(@458752)
// ---------------------------------------------------------------------------
__global__ __launch_bounds__(256) void k_convert_w(
    const float* w0, const float* w1, const float* w2, const float* w3,
    const float* w4, const float* w5, const float* w6, const float* w7,
    unsigned short* out)
{
    int i = blockIdx.x * 256 + threadIdx.x;
    if (i >= 720896) return;
    float v;
    if (i < 458752) {
        int r = i >> 16, j = i & 65535;
        const float* s =
            (r == 0) ? w0 : (r == 1) ? w1 : (r == 2) ? w2 :
            (r == 3) ? w3 : (r == 4) ? w4 : (r == 5) ? w5 : w6;
        v = s[j];
    } else {
        v = w7[i - 458752];
    }
    out[i] = (short)f2bf(v);
}

// ---------------------------------------------------------------------------
// X conversion: q1,q2,q3 (each 8388608 fp32) -> bf16, concatenated in Xb.
// ---------------------------------------------------------------------------
__global__ __launch_bounds__(256) void k_convert_x(
    const float* __restrict__ q1, const float* __restrict__ q2,
    const float* __restrict__ q3, unsigned short* __restrict__ Xb)
{
    const int gi = (blockIdx.x * 256 + threadIdx.x) * 8;
    const float* s = (gi < 8388608) ? q1 : (gi < 16777216) ? q2 : q3;
    const int off = gi & 8388607;
    float4 f0 = *(const float4*)(s + off);
    float4 f1 = *(const float4*)(s + off + 4);
    unsigned a0, a1, a2, a3;
    CVT_PK(a0, f0.x, f0.y);
    CVT_PK(a1, f0.z, f0.w);
    CVT_PK(a2, f1.x, f1.y);
    CVT_PK(a3, f1.z, f1.w);
    uint4 pk; pk.x = a0; pk.y = a1; pk.z = a2; pk.w = a3;
    *(uint4*)(Xb + gi) = pk;
}

// ---------------------------------------------------------------------------
// Linear + tanh, grouped by input:  Y(bf16) = tanh(Xb(bf16) @ W^T + bias)
// (Q outputs, zidx<=3, additionally scaled by SM_SCALE — consumed only by QK^T)
// grid = 2560 (XCD-swizzled), block = 512 (8 waves: 2m x 4n, tile 64x32/out).
// global_load_lds width-16 staging, unpadded [128][32] tiles, double-buffered.
// ---------------------------------------------------------------------------
__global__ __launch_bounds__(512, 4) void k_linear(
    const unsigned short* __restrict__ Xb, const int* __restrict__ adj,
    const unsigned short* __restrict__ wb,
    const float* __restrict__ bQ, const float* __restrict__ bV,
    const float* __restrict__ bQ3, const float* __restrict__ bK3,
    const float* __restrict__ bV3, const float* __restrict__ bQ4,
    const float* __restrict__ bV4,
    unsigned short* __restrict__ lin)
{
    __shared__ __align__(16) short lds[24576];   // 2 bufs x (A|B0|B1) x 4096 sh
    const int bid0 = blockIdx.x;                 // 2560 = 8 XCD x 320
    const int swz = (bid0 & 7) * 320 + (bid0 >> 3);
    const int var = swz >> 9;
    const int rem = swz & 511;
    const int m0 = (rem >> 1) * 128, n0 = (rem & 1) * 128;

    const unsigned short* X = Xb + (size_t)((var == 0) ? 0 : (var == 1) ? 1 : 2) * 8388608;
    const bool gather = (var == 4);
    const int nout = (var == 3) ? 1 : 2;

    int widx0, widx1 = 0, zidx0, zidx1 = 0;
    const float* bp0;
    const float* bp1 = bQ;
    if (var == 0)      { widx0=0; widx1=1; zidx0=0; zidx1=5; bp0=bQ;  bp1=bV;  }
    else if (var == 1) { widx0=0; widx1=1; zidx0=1; zidx1=6; bp0=bQ;  bp1=bV;  }
    else if (var == 2) { widx0=2; widx1=3; zidx0=2; zidx1=4; bp0=bQ3; bp1=bK3; }
    else if (var == 3) { widx0=4;          zidx0=7;          bp0=bV3;          }
    else               { widx0=5; widx1=6; zidx0=3; zidx1=8; bp0=bQ4; bp1=bV4; }

    const int tid = threadIdx.x;
    const int w = tid >> 6, l = tid & 63;
    const int wm = w >> 2, wn = w & 3;           // 2 x 4 wave grid
    const int lr = l & 15, lk = (l >> 4) * 8, lq = (l >> 4) * 4;

    // staging source addresses: wave w covers tile rows 16w..16w+15
    const int rowT = (w << 4) + (l >> 2);        // 0..127
    const int colT = (l & 3) << 3;               // 0,8,16,24
    const int gm = m0 + rowT;
    const int sm = gather ? (adj[gm >> 8] * 256 + (gm & 255)) : gm;
    const unsigned short* aG  = X + (size_t)sm * 256 + colT;
    const unsigned short* b0G = wb + (size_t)widx0 * 65536 + (size_t)(n0 + rowT) * 256 + colT;
    const unsigned short* b1G = wb + (size_t)widx1 * 65536 + (size_t)(n0 + rowT) * 256 + colT;
    char* ldsB = (char*)lds;
    const int wslice = w << 10;                  // wave-uniform byte offset

    f32x4 acc[2][4][2] = {};

    // prologue: stage step 0 into buf 0
    GLOAD16(aG, ldsB + wslice);
    GLOAD16(b0G, ldsB + 8192 + wslice);
    if (nout == 2) GLOAD16(b1G, ldsB + 16384 + wslice);
    __syncthreads();

    for (int st = 0; st < 8; ++st) {
        const int p = st & 1;
        if (st < 7) {
            const int ko = (st + 1) * 32;
            char* nb = ldsB + (p ^ 1) * 24576;
            GLOAD16(aG + ko, nb + wslice);
            GLOAD16(b0G + ko, nb + 8192 + wslice);
            if (nout == 2) GLOAD16(b1G + ko, nb + 16384 + wslice);
        }
        const short* base = lds + p * 12288;
        bf16x8 af[4], bf0v[2], bf1v[2];
        #pragma unroll
        for (int i = 0; i < 4; ++i)
            af[i] = *(const bf16x8*)&base[(wm * 64 + i * 16 + lr) * 32 + lk];
        #pragma unroll
        for (int j = 0; j < 2; ++j)
            bf0v[j] = *(const bf16x8*)&base[4096 + (wn * 32 + j * 16 + lr) * 32 + lk];
        if (nout == 2)
            #pragma unroll
            for (int j = 0; j < 2; ++j)
                bf1v[j] = *(const bf16x8*)&base[8192 + (wn * 32 + j * 16 + lr) * 32 + lk];
        #pragma unroll
        for (int i = 0; i < 4; ++i)
            #pragma unroll
            for (int j = 0; j < 2; ++j)
                acc[0][i][j] = mfma_bf16(af[i], bf0v[j], acc[0][i][j]);
        if (nout == 2)
            #pragma unroll
            for (int i = 0; i < 4; ++i)
                #pragma unroll
                for (int j = 0; j < 2; ++j)
                    acc[1][i][j] = mfma_bf16(af[i], bf1v[j], acc[1][i][j]);
        __syncthreads();
    }

    // Epilogue: tanh (*SM_SCALE for Q outputs) -> bf16 -> LDS bounce -> stores.
    #pragma unroll
    for (int t = 0; t < 2; ++t)
        if (t < nout) {
            const float* bp = t ? bp1 : bp0;
            const int zi = t ? zidx1 : zidx0;
            const float qs = (zi <= 3) ? SM_SCALE : 1.0f;
            float bv[2];
            #pragma unroll
            for (int j = 0; j < 2; ++j)
                bv[j] = bp[n0 + wn * 32 + j * 16 + lr];
            #pragma unroll
            for (int i = 0; i < 4; ++i)
                #pragma unroll
                for (int j = 0; j < 2; ++j)
                    #pragma unroll
                    for (int r = 0; r < 4; ++r)
                        lds[(wm * 64 + i * 16 + lq + r) * 136 + wn * 32 + j * 16 + lr] =
                            (short)f2bf(fast_tanh(acc[t][i][j][r] + bv[j]) * qs);
            __syncthreads();
            unsigned short* Y = lin + (size_t)zi * 8388608;
            #pragma unroll
            for (int it2 = 0; it2 < 4; ++it2) {
                const int c = tid + it2 * 512;
                const int row = c >> 4, col8 = (c & 15) * 8;
                *(bf16x8*)(Y + (size_t)(m0 + row) * 256 + n0 + col8) =
                    *(const bf16x8*)&lds[row * 136 + col8];
            }
            __syncthreads();
        }
}

// ---------------------------------------------------------------------------
// Denominator partials (Q pre-scaled -> exp2(s) directly), bf16 thread-linear:
//   partial2[(a*32+g)*65536 + tile*16384 + c*2048 + tid*8 + m]  (ushort)
// grid = (4 tiles, 32 groups, 4 attn), block = 256.
// global_load_lds width-16 staging into unpadded [128][32] linear tiles;
// double-buffered [2][Q 8KB|K 8KB] = 32KB; stage it+1 while computing it.
// Round-22: __launch_bounds__(256,5) caps VGPR at 102 -> 5 blocks/CU.
// ---------------------------------------------------------------------------
__global__ __launch_bounds__(256, 5) void k_denom(
    const unsigned short* __restrict__ Qa, const unsigned short* __restrict__ Qb2,
    const unsigned short* __restrict__ Qc, const unsigned short* __restrict__ Qd,
    const unsigned short* __restrict__ Kb, unsigned short* __restrict__ partial2)
{
    __shared__ __align__(16) short lds[2][8192];   // [buf][Q 4096 sh | K 4096 sh]
    const int tid = threadIdx.x, w = tid >> 6, l = tid & 63;
    const int q0 = (blockIdx.x >> 1) * 128, k0 = (blockIdx.x & 1) * 128;
    const int g = blockIdx.y, a = blockIdx.z;
    const unsigned short* Qb = (a == 0) ? Qa : (a == 1) ? Qb2 : (a == 2) ? Qc : Qd;
    const int lr = l & 15, lk = (l >> 4) * 8;

    // staging: lane covers tile rows w*16+(l>>2) and +64, col (l&3)*8
    const int rowA = (w << 4) + (l >> 2);
    const int colA = (l & 3) << 3;
    char* ldsB = (char*)lds;
    const int wsl = w << 10;                       // wave-uniform byte offset

    #define NBASE(nn) ((size_t)((nn) & 127) * 65536 + (size_t)((nn) >> 7) * 32)
    #define STAGE(bf, nn) do {                                                   \
        const size_t bs_ = NBASE(nn);                                            \
        char* d_ = ldsB + (bf) * 16384;                                          \
        GLOAD16(Qb + bs_ + (size_t)(q0 + rowA) * 256 + colA,      d_ + wsl);     \
        GLOAD16(Qb + bs_ + (size_t)(q0 + rowA + 64) * 256 + colA, d_ + 4096 + wsl); \
        GLOAD16(Kb + bs_ + (size_t)(k0 + rowA) * 256 + colA,      d_ + 8192 + wsl); \
        GLOAD16(Kb + bs_ + (size_t)(k0 + rowA + 64) * 256 + colA, d_ + 12288 + wsl); \
    } while (0)

    STAGE(0, g * 32);
    __syncthreads();

    f32x4 eacc[2][8] = {};
    for (int it = 0; it < 32; ++it) {
        const int buf = it & 1;
        if (it < 31) STAGE(buf ^ 1, g * 32 + it + 1);
        const short* qs = lds[buf];
        const short* ks = lds[buf] + 4096;
        bf16x8 aq[2], bk[8];
        #pragma unroll
        for (int i = 0; i < 2; ++i)
            aq[i] = *(const bf16x8*)&qs[(w * 32 + i * 16 + lr) * 32 + lk];
        #pragma unroll
        for (int j = 0; j < 8; ++j)
            bk[j] = *(const bf16x8*)&ks[(j * 16 + lr) * 32 + lk];
        #pragma unroll
        for (int i = 0; i < 2; ++i)
            #pragma unroll
            for (int j = 0; j < 8; ++j) {
                f32x4 s = mfma_bf16(aq[i], bk[j], (f32x4){0.f, 0.f, 0.f, 0.f});
                #pragma unroll
                for (int r = 0; r < 4; ++r)
                    eacc[i][j][r] += __builtin_amdgcn_exp2f(s[r]);
            }
        __syncthreads();
    }
    #undef STAGE
    #undef NBASE

    // bf16 thread-linear store: 8 x b128, fully coalesced per wave.
    const size_t pbase = (((size_t)a * 32 + g) << 16) + (size_t)blockIdx.x * 16384;
    #pragma unroll
    for (int cch = 0; cch < 8; ++cch) {
        const int ii = cch >> 2, jp = (cch & 3) * 2;
        union { unsigned short s[8]; bf16x8 v; } U;
        #pragma unroll
        for (int m = 0; m < 8; ++m)
            U.s[m] = f2bf(eacc[ii][jp + (m >> 2)][m & 3]);
        *(bf16x8*)&partial2[pbase + cch * 2048 + tid * 8] = U.v;
    }
}

// ---------------------------------------------------------------------------
// Reduce 32 bf16 partials -> Dinv = 1/sum, wave-fragment-permuted layout (r11):
//   dinvP[a][w][kp][i][j][h][q16][r],  q = w*64+i*16+q16, k = kp*32+j*16+h*4+r
// grid = (256, 4).
// ---------------------------------------------------------------------------
__global__ __launch_bounds__(256) void k_reduce(
    const unsigned short* __restrict__ partial2, float* __restrict__ dinvP)
{
    const int a = blockIdx.y;
    const int gi = blockIdx.x * 256 + threadIdx.x;
    const unsigned short* p = partial2 + (size_t)a * 2097152 + gi;
    float s = 0.f;
    #pragma unroll
    for (int g = 0; g < 32; ++g) s += bf2f(p[(size_t)g * 65536]);
    // decode gi -> (q,k)
    const int tile = gi >> 14, rem2 = gi & 16383;
    const int cch = rem2 >> 11, tid2 = (rem2 >> 3) & 255, m = rem2 & 7;
    const int ii = cch >> 2, j = (cch & 3) * 2 + (m >> 2), r = m & 3;
    const int w2 = tid2 >> 6, l2 = tid2 & 63;
    const int q = (tile >> 1) * 128 + w2 * 32 + ii * 16 + ((l2 >> 4) * 4) + r;
    const int k = (tile & 1) * 128 + j * 16 + (l2 & 15);
    // permuted dinv offset
    const int w_ = q >> 6, iq = (q >> 4) & 3, q16 = q & 15;
    const int kp = k >> 5, jj = (k >> 4) & 1, h = (k >> 2) & 3, rr = k & 3;
    const int off = (((((((w_ * 8 + kp) * 4 + iq) * 2 + jj) * 4 + h) * 16) + q16) * 4) + rr;
    dinvP[((size_t)a << 16) + off] = 1.0f / s;
}

// ---------------------------------------------------------------------------
// Attention: o = (exp2(s) * Dinv) @ V, s pre-scaled via Q.  grid = 4096
// (XCD-swizzled over (head n, attn a)), block = 256 (4 waves x 64 q-rows).
// LDS exactly 32KB -> 5 blocks/CU; Vt XOR-swizzled; Ks GLOAD16 src-swizzled;
// dinv rotate-prefetched; setprio(1) around MFMA clusters.
// ---------------------------------------------------------------------------
__global__ __launch_bounds__(256) void k_attn(
    const unsigned short* __restrict__ Q1, const unsigned short* __restrict__ Q2,
    const unsigned short* __restrict__ Q3, const unsigned short* __restrict__ Q4,
    const unsigned short* __restrict__ Kb,
    const unsigned short* __restrict__ V1, const unsigned short* __restrict__ V2,
    const unsigned short* __restrict__ V3, const unsigned short* __restrict__ V4,
    const float* __restrict__ dinvP,
    float* __restrict__ outBase, unsigned short* __restrict__ ob4)
{
    __shared__ __align__(16) short Vt[32 * 256];      // V^T swizzled, 16 KB
    __shared__ __align__(16) short Ks[256 * 32];      // K src-swizzled, 16 KB
    const int tid = threadIdx.x, w = tid >> 6, l = tid & 63;
    const int bid = blockIdx.x;
    const int swz = (bid & 7) * 512 + (bid >> 3);
    const int a = swz & 3, n = swz >> 2;
    const int c = n >> 7, b = n & 127;
    const int q16 = l & 15, h = l >> 4;
    const size_t base = (size_t)b * 65536 + (size_t)c * 32;

    const unsigned short* Qb = (a == 0) ? Q1 : (a == 1) ? Q2 : (a == 2) ? Q3 : Q4;
    const unsigned short* Vb = (a == 0) ? V1 : (a == 1) ? V2 : (a == 2) ? V3 : V4;
    const f32x4* dw = (const f32x4*)(dinvP + ((size_t)a << 16)) + l + (size_t)w * 4096;
    float* outp = outBase + (size_t)((a == 2) ? 3 : a) * 8388608;

    // --- stage K via GLOAD16 (linear [256][32] dest; source chunk swizzled) ---
    {
        const int rowK0 = (w << 4) + (l >> 2);     // base row within 64-row strip
        const int cK = l & 3;
        char* ldsKb = (char*)Ks;
        #pragma unroll
        for (int j = 0; j < 4; ++j) {
            const int rK = j * 64 + rowK0;
            const int sc = cK ^ (rK & 3);          // pre-swizzled source chunk
            GLOAD16(Kb + base + (size_t)rK * 256 + sc * 8,
                    ldsKb + j * 4096 + (w << 10));
        }
    }
    // --- stage V^T (reg transpose) with XOR-swizzled columns ---
    {
        const unsigned short* vp = Vb + base + (size_t)tid * 256;
        bf16x8 v0 = *(const bf16x8*)(vp);
        bf16x8 v1 = *(const bf16x8*)(vp + 8);
        bf16x8 v2 = *(const bf16x8*)(vp + 16);
        bf16x8 v3 = *(const bf16x8*)(vp + 24);
        #pragma unroll
        for (int e = 0; e < 8; ++e) {
            const int sc = tid ^ (e << 3);         // (row&7)==e for all quarters
            Vt[(0  + e) * 256 + sc] = v0[e];
            Vt[(8  + e) * 256 + sc] = v1[e];
            Vt[(16 + e) * 256 + sc] = v2[e];
            Vt[(24 + e) * 256 + sc] = v3[e];
        }
    }
    __syncthreads();

    const int q0 = w * 64;
    bf16x8 bq[4];
    #pragma unroll
    for (int i = 0; i < 4; ++i)
        bq[i] = *(const bf16x8*)(Qb + base + (size_t)(q0 + i * 16 + q16) * 256 + h * 8);

    f32x4 dc0 = dw[0];
    f32x4 dc1 = dw[64];

    f32x4 oacc[4][2] = {};
    for (int kp = 0; kp < 8; ++kp) {
        const int kk0 = kp * 32;
        const int kxor = ((kk0 + q16) & 3);        // same for +16 rows
        bf16x8 akA = *(const bf16x8*)&Ks[(kk0 + q16) * 32 + ((h ^ kxor) << 3)];
        bf16x8 akB = *(const bf16x8*)&Ks[(kk0 + 16 + q16) * 32 + ((h ^ kxor) << 3)];
        const int vcol = (kk0 + h * 8) ^ ((q16 & 7) << 3);
        bf16x8 vb0 = *(const bf16x8*)&Vt[q16 * 256 + vcol];
        bf16x8 vb1 = *(const bf16x8*)&Vt[(16 + q16) * 256 + vcol];
        #pragma unroll
        for (int i = 0; i < 4; ++i) {
            const int t = kp * 4 + i;
            f32x4 dn0 = dc0, dn1 = dc1;
            if (t < 31) {
                dn0 = dw[(size_t)(t + 1) * 128];
                dn1 = dw[(size_t)(t + 1) * 128 + 64];
            }
            __builtin_amdgcn_s_setprio(1);
            f32x4 s0 = mfma_bf16(akA, bq[i], (f32x4){0.f, 0.f, 0.f, 0.f});
            f32x4 s1 = mfma_bf16(akB, bq[i], (f32x4){0.f, 0.f, 0.f, 0.f});
            __builtin_amdgcn_s_setprio(0);
            float p0 = __builtin_amdgcn_exp2f(s0[0]) * dc0[0];
            float p1 = __builtin_amdgcn_exp2f(s0[1]) * dc0[1];
            float p2 = __builtin_amdgcn_exp2f(s0[2]) * dc0[2];
            float p3 = __builtin_amdgcn_exp2f(s0[3]) * dc0[3];
            float p4 = __builtin_amdgcn_exp2f(s1[0]) * dc1[0];
            float p5 = __builtin_amdgcn_exp2f(s1[1]) * dc1[1];
            float p6 = __builtin_amdgcn_exp2f(s1[2]) * dc1[2];
            float p7 = __builtin_amdgcn_exp2f(s1[3]) * dc1[3];
            unsigned r0, r1, r2, r3;
            CVT_PK(r0, p0, p1);
            CVT_PK(r1, p2, p3);
            CVT_PK(r2, p4, p5);
            CVT_PK(r3, p6, p7);
            SWAP32(r0, r2); SWAP16(r0, r2);
            SWAP32(r1, r3); SWAP16(r1, r3);
            union { unsigned u[4]; bf16x8 v; } F;
            F.u[0] = r0; F.u[1] = r1; F.u[2] = r2; F.u[3] = r3;
            __builtin_amdgcn_s_setprio(1);
            oacc[i][0] = mfma_bf16(F.v, vb0, oacc[i][0]);
            oacc[i][1] = mfma_bf16(F.v, vb1, oacc[i][1]);
            __builtin_amdgcn_s_setprio(0);
            dc0 = dn0; dc1 = dn1;
        }
    }
    if (a == 3) {
        #pragma unroll
        for (int i = 0; i < 4; ++i)
            #pragma unroll
            for (int d = 0; d < 2; ++d)
                #pragma unroll
                for (int r = 0; r < 4; ++r) {
                    int q = q0 + i * 16 + h * 4 + r;
                    int dc = d * 16 + q16;
                    ob4[(size_t)b * 65536 + (size_t)q * 256 + c * 32 + dc] =
                        f2bf(oacc[i][d][r]);
                }
    } else {
        #pragma unroll
        for (int i = 0; i < 4; ++i)
            #pragma unroll
            for (int d = 0; d < 2; ++d)
                #pragma unroll
                for (int r = 0; r < 4; ++r) {
                    int q = q0 + i * 16 + h * 4 + r;
                    int dc = d * 16 + q16;
                    outp[(size_t)b * 65536 + (size_t)q * 256 + c * 32 + dc] =
                        oacc[i][d][r];
                }
    }
}

// ---------------------------------------------------------------------------
// Final: o5 = tanh(concat(o1..o4) @ W5^T + b5).  M=32768, N=256, K=1024.
// BN=256 — grid 256 blocks x 512 thr (8 waves, 2m x 4n, 64x64/wave).
// ---------------------------------------------------------------------------
__global__ __launch_bounds__(512, 2) void k_final(
    const float* __restrict__ p0, const float* __restrict__ p1,
    const float* __restrict__ p2, const unsigned short* __restrict__ p3,
    const unsigned short* __restrict__ W5b, const float* __restrict__ b5,
    float* __restrict__ out)
{
    __shared__ __align__(16) short As[128 * 72];   // 18 KB
    __shared__ __align__(16) short Bs[256 * 72];   // 36 KB
    const int tid = threadIdx.x, w = tid >> 6, l = tid & 63;
    const int wm = w >> 2, wn = w & 3;             // 2 x 4 wave grid
    const int m0 = blockIdx.x * 128;
    const int lr = l & 15, lk = (l >> 4) * 8, lq = (l >> 4) * 4;

    f32x4 acc[4][4] = {};
    for (int step = 0; step < 16; ++step) {
        const int k0 = step * 64;
        const int kc = k0 & 255;
        __syncthreads();
        if (step < 12) {
            const float* P = (step < 4) ? p0 : (step < 8) ? p1 : p2;
            #pragma unroll
            for (int it = 0; it < 2; ++it) {
                const int cc = tid + it * 512;
                const int row = cc >> 3, ch = cc & 7;
                const float* src = P + (size_t)(m0 + row) * 256 + kc + ch * 8;
                float4 f0 = *(const float4*)src;
                float4 f1 = *(const float4*)(src + 4);
                unsigned a0, a1, a2, a3;
                CVT_PK(a0, f0.x, f0.y);
                CVT_PK(a1, f0.z, f0.w);
                CVT_PK(a2, f1.x, f1.y);
                CVT_PK(a3, f1.z, f1.w);
                uint4 pk; pk.x = a0; pk.y = a1; pk.z = a2; pk.w = a3;
                *(uint4*)&As[row * 72 + ch * 8] = pk;
            }
        } else {
            #pragma unroll
            for (int it = 0; it < 2; ++it) {
                const int cc = tid + it * 512;
                const int row = cc >> 3, ch = cc & 7;
                *(bf16x8*)&As[row * 72 + ch * 8] =
                    *(const bf16x8*)(p3 + (size_t)(m0 + row) * 256 + kc + ch * 8);
            }
        }
        #pragma unroll
        for (int it = 0; it < 4; ++it) {
            const int cc = tid + it * 512;
            const int row = cc >> 3, ch = cc & 7;
            *(bf16x8*)&Bs[row * 72 + ch * 8] =
                *(const bf16x8*)(W5b + (size_t)row * 1024 + k0 + ch * 8);
        }
        __syncthreads();
        #pragma unroll
        for (int kk = 0; kk < 2; ++kk) {
            bf16x8 af[4], bfr[4];
            #pragma unroll
            for (int i = 0; i < 4; ++i)
                af[i] = *(const bf16x8*)&As[(wm * 64 + i * 16 + lr) * 72 + kk * 32 + lk];
            #pragma unroll
            for (int j = 0; j < 4; ++j)
                bfr[j] = *(const bf16x8*)&Bs[(wn * 64 + j * 16 + lr) * 72 + kk * 32 + lk];
            #pragma unroll
            for (int i = 0; i < 4; ++i)
                #pragma unroll
                for (int j = 0; j < 4; ++j)
                    acc[i][j] = mfma_bf16(af[i], bfr[j], acc[i][j]);
        }
    }
    #pragma unroll
    for (int j = 0; j < 4; ++j) {
        int col = wn * 64 + j * 16 + lr;
        float bv = b5[col];
        #pragma unroll
        for (int i = 0; i < 4; ++i) {
            int rowb = m0 + wm * 64 + i * 16 + lq;
            #pragma unroll
            for (int r = 0; r < 4; ++r)
                out[(size_t)(rowb + r) * 256 + col] =
                    fast_tanh(acc[i][j][r] + bv);
        }
    }
}

// ---------------------------------------------------------------------------
extern "C" void kernel_launch(void* const* d_in, const int* in_sizes, int n_in,
                              void* d_out, int out_size, void* d_ws, size_t ws_size,
                              hipStream_t stream)
{
    const float* q1  = (const float*)d_in[0];
    const float* q2  = (const float*)d_in[1];
    const float* q3  = (const float*)d_in[2];
    const int*   adj = (const int*)d_in[3];
    const float* WQ  = (const float*)d_in[4];  const float* bQ  = (const float*)d_in[5];
    const float* WV  = (const float*)d_in[6];  const float* bV  = (const float*)d_in[7];
    const float* WQ3 = (const float*)d_in[8];  const float* bQ3 = (const float*)d_in[9];
    const float* WK3 = (const float*)d_in[10]; const float* bK3 = (const float*)d_in[11];
    const float* WV3 = (const float*)d_in[12]; const float* bV3 = (const float*)d_in[13];
    const float* WQ4 = (const float*)d_in[14]; const float* bQ4 = (const float*)d_in[15];
    const float* WV4 = (const float*)d_in[16]; const float* bV4 = (const float*)d_in[17];
    const float* W5  = (const float*)d_in[18]; const float* b5  = (const float*)d_in[19];

    char* ws = (char*)d_ws;
    unsigned short* wb  = (unsigned short*)ws;               // 720896 bf16 weights
    unsigned short* W5b = wb + 458752;
    unsigned short* lin = (unsigned short*)(ws + 1441792);   // 9 x 32768x256 bf16
    unsigned short* Q1 = lin + 0ull * 8388608;
    unsigned short* Q2 = lin + 1ull * 8388608;
    unsigned short* Q3 = lin + 2ull * 8388608;
    unsigned short* Q4 = lin + 3ull * 8388608;
    unsigned short* K3 = lin + 4ull * 8388608;
    unsigned short* V1 = lin + 5ull * 8388608;
    unsigned short* V2 = lin + 6ull * 8388608;
    unsigned short* V3 = lin + 7ull * 8388608;
    unsigned short* V4 = lin + 8ull * 8388608;
    unsigned short* partial2 = (unsigned short*)(ws + 152436736);  // 4*32*65536 bf16
    float* dinvP   = (float*)(ws + 185991168);               // 4*65536 f32 (permuted)
    unsigned short* ob4 = (unsigned short*)(ws + 152436736); // o4 bf16, overlaps dead partial2

    float* outf = (float*)d_out;   // planes: o1(0) o2(1) o5(2) o3(3)
    float* o5p = outf + 2ull * 8388608;
    unsigned short* Xb = (unsigned short*)d_out;  // q1..q3 bf16 scratch in o1/o2 planes

    dim3 blk(256);

    hipLaunchKernelGGL(k_convert_w, dim3(2816), blk, 0, stream,
                       WQ, WV, WQ3, WK3, WV3, WQ4, WV4, W5, wb);
    hipLaunchKernelGGL(k_convert_x, dim3(12288), blk, 0, stream,
                       q1, q2, q3, Xb);

    hipLaunchKernelGGL(k_linear, dim3(2560), dim3(512), 0, stream,
                       Xb, adj, wb,
                       bQ, bV, bQ3, bK3, bV3, bQ4, bV4, lin);

    hipLaunchKernelGGL(k_denom, dim3(4, 32, 4), blk, 0, stream,
                       Q1, Q2, Q3, Q4, K3, partial2);
    hipLaunchKernelGGL(k_reduce, dim3(256, 4), blk, 0, stream, partial2, dinvP);

    hipLaunchKernelGGL(k_attn, dim3(4096), blk, 0, stream,
                       Q1, Q2, Q3, Q4, K3, V1, V2, V3, V4, dinvP,
                       outf, ob4);

    hipLaunchKernelGGL(k_final, dim3(256), dim3(512), 0, stream,
                       outf, outf + 8388608ull, outf + 3ull * 8388608, ob4,
                       W5b, b5, o5p);
}

// Round 23
// 280.594 us; speedup vs baseline: 1.3041x; 1.3041x over previous
//
#include <hip/hip_runtime.h>

// ---------------------------------------------------------------------------
// multihead_attention_87454124081549 — round 23 (= round 21 exact, best 281us)
// Round-22's k_denom __launch_bounds__(256,5) forced VGPR 104->48 and spilled
// eacc to scratch (WRITE_SIZE 67->180MB, k_denom 45->130us). Reverted.
// JOURNAL: launch_bounds min-waves is a hard allocator constraint — check
// kernel-resource-usage before spending a bench. exp2-fold of dinv FAILED
// twice (r8/r9); r12/r13/r19/r22 net-negative; r18 dinv rotation load-bearing.
// Trail: 804->537->531->517->456->389->343->335->330->322->306->293->288->284->281.
// ---------------------------------------------------------------------------

typedef __attribute__((ext_vector_type(4))) float f32x4;
typedef __attribute__((ext_vector_type(8))) short bf16x8;

#define LOG2E 1.4426950408889634f
#define SM_SCALE (1.4426950408889634f / 5.656854249492381f)  // log2(e)/sqrt(32)

#define CVT_PK(d, lo, hi) \
    asm("v_cvt_pk_bf16_f32 %0, %1, %2" : "=v"(d) : "v"(lo), "v"(hi))
#define SWAP32(x, y) \
    asm("v_permlane32_swap_b32 %0, %1" : "+v"(x), "+v"(y))
#define SWAP16(x, y) \
    asm("v_permlane16_swap_b32 %0, %1" : "+v"(x), "+v"(y))
#define GLOAD16(g, p) __builtin_amdgcn_global_load_lds( \
    (const __attribute__((address_space(1))) void*)(g), \
    (__attribute__((address_space(3))) void*)(p), 16, 0, 0)

__device__ __forceinline__ unsigned short f2bf(float x) {
    union { float f; unsigned u; } v; v.f = x;
    unsigned r = v.u + 0x7FFFu + ((v.u >> 16) & 1u);   // RNE
    return (unsigned short)(r >> 16);
}

__device__ __forceinline__ float bf2f(unsigned short x) {
    union { unsigned u; float f; } v; v.u = ((unsigned)x) << 16;
    return v.f;
}

__device__ __forceinline__ float fast_tanh(float x) {
    float e = __builtin_amdgcn_exp2f(x * (2.0f * LOG2E));   // exp(2x)
    return 1.0f - 2.0f * __builtin_amdgcn_rcpf(e + 1.0f);
}

__device__ __forceinline__ f32x4 mfma_bf16(bf16x8 a, bf16x8 b, f32x4 c) {
    return __builtin_amdgcn_mfma_f32_16x16x32_bf16(a, b, c, 0, 0, 0);
}

// ---------------------------------------------------------------------------
// Weight conversion: 7 x (256x256) + W5 (256x1024) fp32 -> bf16, concatenated.
// Order: WQ(0) WV(1) WQ3(2) WK3(3) WV3(4) WQ4(5) WV4(6) W5(@458752)
// ---------------------------------------------------------------------------
__global__ __launch_bounds__(256) void k_convert_w(
    const float* w0, const float* w1, const float* w2, const float* w3,
    const float* w4, const float* w5, const float* w6, const float* w7,
    unsigned short* out)
{
    int i = blockIdx.x * 256 + threadIdx.x;
    if (i >= 720896) return;
    float v;
    if (i < 458752) {
        int r = i >> 16, j = i & 65535;
        const float* s =
            (r == 0) ? w0 : (r == 1) ? w1 : (r == 2) ? w2 :
            (r == 3) ? w3 : (r == 4) ? w4 : (r == 5) ? w5 : w6;
        v = s[j];
    } else {
        v = w7[i - 458752];
    }
    out[i] = (short)f2bf(v);
}

// ---------------------------------------------------------------------------
// X conversion: q1,q2,q3 (each 8388608 fp32) -> bf16, concatenated in Xb.
// ---------------------------------------------------------------------------
__global__ __launch_bounds__(256) void k_convert_x(
    const float* __restrict__ q1, const float* __restrict__ q2,
    const float* __restrict__ q3, unsigned short* __restrict__ Xb)
{
    const int gi = (blockIdx.x * 256 + threadIdx.x) * 8;
    const float* s = (gi < 8388608) ? q1 : (gi < 16777216) ? q2 : q3;
    const int off = gi & 8388607;
    float4 f0 = *(const float4*)(s + off);
    float4 f1 = *(const float4*)(s + off + 4);
    unsigned a0, a1, a2, a3;
    CVT_PK(a0, f0.x, f0.y);
    CVT_PK(a1, f0.z, f0.w);
    CVT_PK(a2, f1.x, f1.y);
    CVT_PK(a3, f1.z, f1.w);
    uint4 pk; pk.x = a0; pk.y = a1; pk.z = a2; pk.w = a3;
    *(uint4*)(Xb + gi) = pk;
}

// ---------------------------------------------------------------------------
// Linear + tanh, grouped by input:  Y(bf16) = tanh(Xb(bf16) @ W^T + bias)
// (Q outputs, zidx<=3, additionally scaled by SM_SCALE — consumed only by QK^T)
// grid = 2560 (XCD-swizzled), block = 512 (8 waves: 2m x 4n, tile 64x32/out).
// global_load_lds width-16 staging, unpadded [128][32] tiles, double-buffered.
// ---------------------------------------------------------------------------
__global__ __launch_bounds__(512, 4) void k_linear(
    const unsigned short* __restrict__ Xb, const int* __restrict__ adj,
    const unsigned short* __restrict__ wb,
    const float* __restrict__ bQ, const float* __restrict__ bV,
    const float* __restrict__ bQ3, const float* __restrict__ bK3,
    const float* __restrict__ bV3, const float* __restrict__ bQ4,
    const float* __restrict__ bV4,
    unsigned short* __restrict__ lin)
{
    __shared__ __align__(16) short lds[24576];   // 2 bufs x (A|B0|B1) x 4096 sh
    const int bid0 = blockIdx.x;                 // 2560 = 8 XCD x 320
    const int swz = (bid0 & 7) * 320 + (bid0 >> 3);
    const int var = swz >> 9;
    const int rem = swz & 511;
    const int m0 = (rem >> 1) * 128, n0 = (rem & 1) * 128;

    const unsigned short* X = Xb + (size_t)((var == 0) ? 0 : (var == 1) ? 1 : 2) * 8388608;
    const bool gather = (var == 4);
    const int nout = (var == 3) ? 1 : 2;

    int widx0, widx1 = 0, zidx0, zidx1 = 0;
    const float* bp0;
    const float* bp1 = bQ;
    if (var == 0)      { widx0=0; widx1=1; zidx0=0; zidx1=5; bp0=bQ;  bp1=bV;  }
    else if (var == 1) { widx0=0; widx1=1; zidx0=1; zidx1=6; bp0=bQ;  bp1=bV;  }
    else if (var == 2) { widx0=2; widx1=3; zidx0=2; zidx1=4; bp0=bQ3; bp1=bK3; }
    else if (var == 3) { widx0=4;          zidx0=7;          bp0=bV3;          }
    else               { widx0=5; widx1=6; zidx0=3; zidx1=8; bp0=bQ4; bp1=bV4; }

    const int tid = threadIdx.x;
    const int w = tid >> 6, l = tid & 63;
    const int wm = w >> 2, wn = w & 3;           // 2 x 4 wave grid
    const int lr = l & 15, lk = (l >> 4) * 8, lq = (l >> 4) * 4;

    // staging source addresses: wave w covers tile rows 16w..16w+15
    const int rowT = (w << 4) + (l >> 2);        // 0..127
    const int colT = (l & 3) << 3;               // 0,8,16,24
    const int gm = m0 + rowT;
    const int sm = gather ? (adj[gm >> 8] * 256 + (gm & 255)) : gm;
    const unsigned short* aG  = X + (size_t)sm * 256 + colT;
    const unsigned short* b0G = wb + (size_t)widx0 * 65536 + (size_t)(n0 + rowT) * 256 + colT;
    const unsigned short* b1G = wb + (size_t)widx1 * 65536 + (size_t)(n0 + rowT) * 256 + colT;
    char* ldsB = (char*)lds;
    const int wslice = w << 10;                  // wave-uniform byte offset

    f32x4 acc[2][4][2] = {};

    // prologue: stage step 0 into buf 0
    GLOAD16(aG, ldsB + wslice);
    GLOAD16(b0G, ldsB + 8192 + wslice);
    if (nout == 2) GLOAD16(b1G, ldsB + 16384 + wslice);
    __syncthreads();

    for (int st = 0; st < 8; ++st) {
        const int p = st & 1;
        if (st < 7) {
            const int ko = (st + 1) * 32;
            char* nb = ldsB + (p ^ 1) * 24576;
            GLOAD16(aG + ko, nb + wslice);
            GLOAD16(b0G + ko, nb + 8192 + wslice);
            if (nout == 2) GLOAD16(b1G + ko, nb + 16384 + wslice);
        }
        const short* base = lds + p * 12288;
        bf16x8 af[4], bf0v[2], bf1v[2];
        #pragma unroll
        for (int i = 0; i < 4; ++i)
            af[i] = *(const bf16x8*)&base[(wm * 64 + i * 16 + lr) * 32 + lk];
        #pragma unroll
        for (int j = 0; j < 2; ++j)
            bf0v[j] = *(const bf16x8*)&base[4096 + (wn * 32 + j * 16 + lr) * 32 + lk];
        if (nout == 2)
            #pragma unroll
            for (int j = 0; j < 2; ++j)
                bf1v[j] = *(const bf16x8*)&base[8192 + (wn * 32 + j * 16 + lr) * 32 + lk];
        #pragma unroll
        for (int i = 0; i < 4; ++i)
            #pragma unroll
            for (int j = 0; j < 2; ++j)
                acc[0][i][j] = mfma_bf16(af[i], bf0v[j], acc[0][i][j]);
        if (nout == 2)
            #pragma unroll
            for (int i = 0; i < 4; ++i)
                #pragma unroll
                for (int j = 0; j < 2; ++j)
                    acc[1][i][j] = mfma_bf16(af[i], bf1v[j], acc[1][i][j]);
        __syncthreads();
    }

    // Epilogue: tanh (*SM_SCALE for Q outputs) -> bf16 -> LDS bounce -> stores.
    #pragma unroll
    for (int t = 0; t < 2; ++t)
        if (t < nout) {
            const float* bp = t ? bp1 : bp0;
            const int zi = t ? zidx1 : zidx0;
            const float qs = (zi <= 3) ? SM_SCALE : 1.0f;
            float bv[2];
            #pragma unroll
            for (int j = 0; j < 2; ++j)
                bv[j] = bp[n0 + wn * 32 + j * 16 + lr];
            #pragma unroll
            for (int i = 0; i < 4; ++i)
                #pragma unroll
                for (int j = 0; j < 2; ++j)
                    #pragma unroll
                    for (int r = 0; r < 4; ++r)
                        lds[(wm * 64 + i * 16 + lq + r) * 136 + wn * 32 + j * 16 + lr] =
                            (short)f2bf(fast_tanh(acc[t][i][j][r] + bv[j]) * qs);
            __syncthreads();
            unsigned short* Y = lin + (size_t)zi * 8388608;
            #pragma unroll
            for (int it2 = 0; it2 < 4; ++it2) {
                const int c = tid + it2 * 512;
                const int row = c >> 4, col8 = (c & 15) * 8;
                *(bf16x8*)(Y + (size_t)(m0 + row) * 256 + n0 + col8) =
                    *(const bf16x8*)&lds[row * 136 + col8];
            }
            __syncthreads();
        }
}

// ---------------------------------------------------------------------------
// Denominator partials (Q pre-scaled -> exp2(s) directly), bf16 thread-linear:
//   partial2[(a*32+g)*65536 + tile*16384 + c*2048 + tid*8 + m]  (ushort)
// grid = (4 tiles, 32 groups, 4 attn), block = 256.
// global_load_lds width-16 staging into unpadded [128][32] linear tiles;
// double-buffered [2][Q 8KB|K 8KB] = 32KB; stage it+1 while computing it.
// ---------------------------------------------------------------------------
__global__ __launch_bounds__(256) void k_denom(
    const unsigned short* __restrict__ Qa, const unsigned short* __restrict__ Qb2,
    const unsigned short* __restrict__ Qc, const unsigned short* __restrict__ Qd,
    const unsigned short* __restrict__ Kb, unsigned short* __restrict__ partial2)
{
    __shared__ __align__(16) short lds[2][8192];   // [buf][Q 4096 sh | K 4096 sh]
    const int tid = threadIdx.x, w = tid >> 6, l = tid & 63;
    const int q0 = (blockIdx.x >> 1) * 128, k0 = (blockIdx.x & 1) * 128;
    const int g = blockIdx.y, a = blockIdx.z;
    const unsigned short* Qb = (a == 0) ? Qa : (a == 1) ? Qb2 : (a == 2) ? Qc : Qd;
    const int lr = l & 15, lk = (l >> 4) * 8;

    // staging: lane covers tile rows w*16+(l>>2) and +64, col (l&3)*8
    const int rowA = (w << 4) + (l >> 2);
    const int colA = (l & 3) << 3;
    char* ldsB = (char*)lds;
    const int wsl = w << 10;                       // wave-uniform byte offset

    #define NBASE(nn) ((size_t)((nn) & 127) * 65536 + (size_t)((nn) >> 7) * 32)
    #define STAGE(bf, nn) do {                                                   \
        const size_t bs_ = NBASE(nn);                                            \
        char* d_ = ldsB + (bf) * 16384;                                          \
        GLOAD16(Qb + bs_ + (size_t)(q0 + rowA) * 256 + colA,      d_ + wsl);     \
        GLOAD16(Qb + bs_ + (size_t)(q0 + rowA + 64) * 256 + colA, d_ + 4096 + wsl); \
        GLOAD16(Kb + bs_ + (size_t)(k0 + rowA) * 256 + colA,      d_ + 8192 + wsl); \
        GLOAD16(Kb + bs_ + (size_t)(k0 + rowA + 64) * 256 + colA, d_ + 12288 + wsl); \
    } while (0)

    STAGE(0, g * 32);
    __syncthreads();

    f32x4 eacc[2][8] = {};
    for (int it = 0; it < 32; ++it) {
        const int buf = it & 1;
        if (it < 31) STAGE(buf ^ 1, g * 32 + it + 1);
        const short* qs = lds[buf];
        const short* ks = lds[buf] + 4096;
        bf16x8 aq[2], bk[8];
        #pragma unroll
        for (int i = 0; i < 2; ++i)
            aq[i] = *(const bf16x8*)&qs[(w * 32 + i * 16 + lr) * 32 + lk];
        #pragma unroll
        for (int j = 0; j < 8; ++j)
            bk[j] = *(const bf16x8*)&ks[(j * 16 + lr) * 32 + lk];
        #pragma unroll
        for (int i = 0; i < 2; ++i)
            #pragma unroll
            for (int j = 0; j < 8; ++j) {
                f32x4 s = mfma_bf16(aq[i], bk[j], (f32x4){0.f, 0.f, 0.f, 0.f});
                #pragma unroll
                for (int r = 0; r < 4; ++r)
                    eacc[i][j][r] += __builtin_amdgcn_exp2f(s[r]);
            }
        __syncthreads();
    }
    #undef STAGE
    #undef NBASE

    // bf16 thread-linear store: 8 x b128, fully coalesced per wave.
    const size_t pbase = (((size_t)a * 32 + g) << 16) + (size_t)blockIdx.x * 16384;
    #pragma unroll
    for (int cch = 0; cch < 8; ++cch) {
        const int ii = cch >> 2, jp = (cch & 3) * 2;
        union { unsigned short s[8]; bf16x8 v; } U;
        #pragma unroll
        for (int m = 0; m < 8; ++m)
            U.s[m] = f2bf(eacc[ii][jp + (m >> 2)][m & 3]);
        *(bf16x8*)&partial2[pbase + cch * 2048 + tid * 8] = U.v;
    }
}

// ---------------------------------------------------------------------------
// Reduce 32 bf16 partials -> Dinv = 1/sum, wave-fragment-permuted layout (r11):
//   dinvP[a][w][kp][i][j][h][q16][r],  q = w*64+i*16+q16, k = kp*32+j*16+h*4+r
// grid = (256, 4).
// ---------------------------------------------------------------------------
__global__ __launch_bounds__(256) void k_reduce(
    const unsigned short* __restrict__ partial2, float* __restrict__ dinvP)
{
    const int a = blockIdx.y;
    const int gi = blockIdx.x * 256 + threadIdx.x;
    const unsigned short* p = partial2 + (size_t)a * 2097152 + gi;
    float s = 0.f;
    #pragma unroll
    for (int g = 0; g < 32; ++g) s += bf2f(p[(size_t)g * 65536]);
    // decode gi -> (q,k)
    const int tile = gi >> 14, rem2 = gi & 16383;
    const int cch = rem2 >> 11, tid2 = (rem2 >> 3) & 255, m = rem2 & 7;
    const int ii = cch >> 2, j = (cch & 3) * 2 + (m >> 2), r = m & 3;
    const int w2 = tid2 >> 6, l2 = tid2 & 63;
    const int q = (tile >> 1) * 128 + w2 * 32 + ii * 16 + ((l2 >> 4) * 4) + r;
    const int k = (tile & 1) * 128 + j * 16 + (l2 & 15);
    // permuted dinv offset
    const int w_ = q >> 6, iq = (q >> 4) & 3, q16 = q & 15;
    const int kp = k >> 5, jj = (k >> 4) & 1, h = (k >> 2) & 3, rr = k & 3;
    const int off = (((((((w_ * 8 + kp) * 4 + iq) * 2 + jj) * 4 + h) * 16) + q16) * 4) + rr;
    dinvP[((size_t)a << 16) + off] = 1.0f / s;
}

// ---------------------------------------------------------------------------
// Attention: o = (exp2(s) * Dinv) @ V, s pre-scaled via Q.  grid = 4096
// (XCD-swizzled over (head n, attn a)), block = 256 (4 waves x 64 q-rows).
// LDS exactly 32KB -> 5 blocks/CU:
//   Vt [32][256] XOR-swizzled (col ^ (row&7)<<3), reg-staged transpose writes;
//   Ks [256][32] via GLOAD16 with source chunk pre-swizzle (c ^ (row&3)),
//   read chunk h ^ ((kk0+q16)&3). Both reads <=2-way bank alias (free).
// dinv rotate-prefetched; setprio(1) around MFMA clusters.
// ---------------------------------------------------------------------------
__global__ __launch_bounds__(256) void k_attn(
    const unsigned short* __restrict__ Q1, const unsigned short* __restrict__ Q2,
    const unsigned short* __restrict__ Q3, const unsigned short* __restrict__ Q4,
    const unsigned short* __restrict__ Kb,
    const unsigned short* __restrict__ V1, const unsigned short* __restrict__ V2,
    const unsigned short* __restrict__ V3, const unsigned short* __restrict__ V4,
    const float* __restrict__ dinvP,
    float* __restrict__ outBase, unsigned short* __restrict__ ob4)
{
    __shared__ __align__(16) short Vt[32 * 256];      // V^T swizzled, 16 KB
    __shared__ __align__(16) short Ks[256 * 32];      // K src-swizzled, 16 KB
    const int tid = threadIdx.x, w = tid >> 6, l = tid & 63;
    const int bid = blockIdx.x;
    const int swz = (bid & 7) * 512 + (bid >> 3);
    const int a = swz & 3, n = swz >> 2;
    const int c = n >> 7, b = n & 127;
    const int q16 = l & 15, h = l >> 4;
    const size_t base = (size_t)b * 65536 + (size_t)c * 32;

    const unsigned short* Qb = (a == 0) ? Q1 : (a == 1) ? Q2 : (a == 2) ? Q3 : Q4;
    const unsigned short* Vb = (a == 0) ? V1 : (a == 1) ? V2 : (a == 2) ? V3 : V4;
    const f32x4* dw = (const f32x4*)(dinvP + ((size_t)a << 16)) + l + (size_t)w * 4096;
    float* outp = outBase + (size_t)((a == 2) ? 3 : a) * 8388608;

    // --- stage K via GLOAD16 (linear [256][32] dest; source chunk swizzled) ---
    {
        const int rowK0 = (w << 4) + (l >> 2);     // base row within 64-row strip
        const int cK = l & 3;
        char* ldsKb = (char*)Ks;
        #pragma unroll
        for (int j = 0; j < 4; ++j) {
            const int rK = j * 64 + rowK0;
            const int sc = cK ^ (rK & 3);          // pre-swizzled source chunk
            GLOAD16(Kb + base + (size_t)rK * 256 + sc * 8,
                    ldsKb + j * 4096 + (w << 10));
        }
    }
    // --- stage V^T (reg transpose) with XOR-swizzled columns ---
    {
        const unsigned short* vp = Vb + base + (size_t)tid * 256;
        bf16x8 v0 = *(const bf16x8*)(vp);
        bf16x8 v1 = *(const bf16x8*)(vp + 8);
        bf16x8 v2 = *(const bf16x8*)(vp + 16);
        bf16x8 v3 = *(const bf16x8*)(vp + 24);
        #pragma unroll
        for (int e = 0; e < 8; ++e) {
            const int sc = tid ^ (e << 3);         // (row&7)==e for all quarters
            Vt[(0  + e) * 256 + sc] = v0[e];
            Vt[(8  + e) * 256 + sc] = v1[e];
            Vt[(16 + e) * 256 + sc] = v2[e];
            Vt[(24 + e) * 256 + sc] = v3[e];
        }
    }
    __syncthreads();

    const int q0 = w * 64;
    bf16x8 bq[4];
    #pragma unroll
    for (int i = 0; i < 4; ++i)
        bq[i] = *(const bf16x8*)(Qb + base + (size_t)(q0 + i * 16 + q16) * 256 + h * 8);

    f32x4 dc0 = dw[0];
    f32x4 dc1 = dw[64];

    f32x4 oacc[4][2] = {};
    for (int kp = 0; kp < 8; ++kp) {
        const int kk0 = kp * 32;
        const int kxor = ((kk0 + q16) & 3);        // same for +16 rows
        bf16x8 akA = *(const bf16x8*)&Ks[(kk0 + q16) * 32 + ((h ^ kxor) << 3)];
        bf16x8 akB = *(const bf16x8*)&Ks[(kk0 + 16 + q16) * 32 + ((h ^ kxor) << 3)];
        const int vcol = (kk0 + h * 8) ^ ((q16 & 7) << 3);
        bf16x8 vb0 = *(const bf16x8*)&Vt[q16 * 256 + vcol];
        bf16x8 vb1 = *(const bf16x8*)&Vt[(16 + q16) * 256 + vcol];
        #pragma unroll
        for (int i = 0; i < 4; ++i) {
            const int t = kp * 4 + i;
            f32x4 dn0 = dc0, dn1 = dc1;
            if (t < 31) {
                dn0 = dw[(size_t)(t + 1) * 128];
                dn1 = dw[(size_t)(t + 1) * 128 + 64];
            }
            __builtin_amdgcn_s_setprio(1);
            f32x4 s0 = mfma_bf16(akA, bq[i], (f32x4){0.f, 0.f, 0.f, 0.f});
            f32x4 s1 = mfma_bf16(akB, bq[i], (f32x4){0.f, 0.f, 0.f, 0.f});
            __builtin_amdgcn_s_setprio(0);
            float p0 = __builtin_amdgcn_exp2f(s0[0]) * dc0[0];
            float p1 = __builtin_amdgcn_exp2f(s0[1]) * dc0[1];
            float p2 = __builtin_amdgcn_exp2f(s0[2]) * dc0[2];
            float p3 = __builtin_amdgcn_exp2f(s0[3]) * dc0[3];
            float p4 = __builtin_amdgcn_exp2f(s1[0]) * dc1[0];
            float p5 = __builtin_amdgcn_exp2f(s1[1]) * dc1[1];
            float p6 = __builtin_amdgcn_exp2f(s1[2]) * dc1[2];
            float p7 = __builtin_amdgcn_exp2f(s1[3]) * dc1[3];
            unsigned r0, r1, r2, r3;
            CVT_PK(r0, p0, p1);
            CVT_PK(r1, p2, p3);
            CVT_PK(r2, p4, p5);
            CVT_PK(r3, p6, p7);
            SWAP32(r0, r2); SWAP16(r0, r2);
            SWAP32(r1, r3); SWAP16(r1, r3);
            union { unsigned u[4]; bf16x8 v; } F;
            F.u[0] = r0; F.u[1] = r1; F.u[2] = r2; F.u[3] = r3;
            __builtin_amdgcn_s_setprio(1);
            oacc[i][0] = mfma_bf16(F.v, vb0, oacc[i][0]);
            oacc[i][1] = mfma_bf16(F.v, vb1, oacc[i][1]);
            __builtin_amdgcn_s_setprio(0);
            dc0 = dn0; dc1 = dn1;
        }
    }
    if (a == 3) {
        #pragma unroll
        for (int i = 0; i < 4; ++i)
            #pragma unroll
            for (int d = 0; d < 2; ++d)
                #pragma unroll
                for (int r = 0; r < 4; ++r) {
                    int q = q0 + i * 16 + h * 4 + r;
                    int dc = d * 16 + q16;
                    ob4[(size_t)b * 65536 + (size_t)q * 256 + c * 32 + dc] =
                        f2bf(oacc[i][d][r]);
                }
    } else {
        #pragma unroll
        for (int i = 0; i < 4; ++i)
            #pragma unroll
            for (int d = 0; d < 2; ++d)
                #pragma unroll
                for (int r = 0; r < 4; ++r) {
                    int q = q0 + i * 16 + h * 4 + r;
                    int dc = d * 16 + q16;
                    outp[(size_t)b * 65536 + (size_t)q * 256 + c * 32 + dc] =
                        oacc[i][d][r];
                }
    }
}

// ---------------------------------------------------------------------------
// Final: o5 = tanh(concat(o1..o4) @ W5^T + b5).  M=32768, N=256, K=1024.
// BN=256 — grid 256 blocks x 512 thr (8 waves, 2m x 4n, 64x64/wave).
// ---------------------------------------------------------------------------
__global__ __launch_bounds__(512, 2) void k_final(
    const float* __restrict__ p0, const float* __restrict__ p1,
    const float* __restrict__ p2, const unsigned short* __restrict__ p3,
    const unsigned short* __restrict__ W5b, const float* __restrict__ b5,
    float* __restrict__ out)
{
    __shared__ __align__(16) short As[128 * 72];   // 18 KB
    __shared__ __align__(16) short Bs[256 * 72];   // 36 KB
    const int tid = threadIdx.x, w = tid >> 6, l = tid & 63;
    const int wm = w >> 2, wn = w & 3;             // 2 x 4 wave grid
    const int m0 = blockIdx.x * 128;
    const int lr = l & 15, lk = (l >> 4) * 8, lq = (l >> 4) * 4;

    f32x4 acc[4][4] = {};
    for (int step = 0; step < 16; ++step) {
        const int k0 = step * 64;
        const int kc = k0 & 255;
        __syncthreads();
        if (step < 12) {
            const float* P = (step < 4) ? p0 : (step < 8) ? p1 : p2;
            #pragma unroll
            for (int it = 0; it < 2; ++it) {
                const int cc = tid + it * 512;
                const int row = cc >> 3, ch = cc & 7;
                const float* src = P + (size_t)(m0 + row) * 256 + kc + ch * 8;
                float4 f0 = *(const float4*)src;
                float4 f1 = *(const float4*)(src + 4);
                unsigned a0, a1, a2, a3;
                CVT_PK(a0, f0.x, f0.y);
                CVT_PK(a1, f0.z, f0.w);
                CVT_PK(a2, f1.x, f1.y);
                CVT_PK(a3, f1.z, f1.w);
                uint4 pk; pk.x = a0; pk.y = a1; pk.z = a2; pk.w = a3;
                *(uint4*)&As[row * 72 + ch * 8] = pk;
            }
        } else {
            #pragma unroll
            for (int it = 0; it < 2; ++it) {
                const int cc = tid + it * 512;
                const int row = cc >> 3, ch = cc & 7;
                *(bf16x8*)&As[row * 72 + ch * 8] =
                    *(const bf16x8*)(p3 + (size_t)(m0 + row) * 256 + kc + ch * 8);
            }
        }
        #pragma unroll
        for (int it = 0; it < 4; ++it) {
            const int cc = tid + it * 512;
            const int row = cc >> 3, ch = cc & 7;
            *(bf16x8*)&Bs[row * 72 + ch * 8] =
                *(const bf16x8*)(W5b + (size_t)row * 1024 + k0 + ch * 8);
        }
        __syncthreads();
        #pragma unroll
        for (int kk = 0; kk < 2; ++kk) {
            bf16x8 af[4], bfr[4];
            #pragma unroll
            for (int i = 0; i < 4; ++i)
                af[i] = *(const bf16x8*)&As[(wm * 64 + i * 16 + lr) * 72 + kk * 32 + lk];
            #pragma unroll
            for (int j = 0; j < 4; ++j)
                bfr[j] = *(const bf16x8*)&Bs[(wn * 64 + j * 16 + lr) * 72 + kk * 32 + lk];
            #pragma unroll
            for (int i = 0; i < 4; ++i)
                #pragma unroll
                for (int j = 0; j < 4; ++j)
                    acc[i][j] = mfma_bf16(af[i], bfr[j], acc[i][j]);
        }
    }
    #pragma unroll
    for (int j = 0; j < 4; ++j) {
        int col = wn * 64 + j * 16 + lr;
        float bv = b5[col];
        #pragma unroll
        for (int i = 0; i < 4; ++i) {
            int rowb = m0 + wm * 64 + i * 16 + lq;
            #pragma unroll
            for (int r = 0; r < 4; ++r)
                out[(size_t)(rowb + r) * 256 + col] =
                    fast_tanh(acc[i][j][r] + bv);
        }
    }
}

// ---------------------------------------------------------------------------
extern "C" void kernel_launch(void* const* d_in, const int* in_sizes, int n_in,
                              void* d_out, int out_size, void* d_ws, size_t ws_size,
                              hipStream_t stream)
{
    const float* q1  = (const float*)d_in[0];
    const float* q2  = (const float*)d_in[1];
    const float* q3  = (const float*)d_in[2];
    const int*   adj = (const int*)d_in[3];
    const float* WQ  = (const float*)d_in[4];  const float* bQ  = (const float*)d_in[5];
    const float* WV  = (const float*)d_in[6];  const float* bV  = (const float*)d_in[7];
    const float* WQ3 = (const float*)d_in[8];  const float* bQ3 = (const float*)d_in[9];
    const float* WK3 = (const float*)d_in[10]; const float* bK3 = (const float*)d_in[11];
    const float* WV3 = (const float*)d_in[12]; const float* bV3 = (const float*)d_in[13];
    const float* WQ4 = (const float*)d_in[14]; const float* bQ4 = (const float*)d_in[15];
    const float* WV4 = (const float*)d_in[16]; const float* bV4 = (const float*)d_in[17];
    const float* W5  = (const float*)d_in[18]; const float* b5  = (const float*)d_in[19];

    char* ws = (char*)d_ws;
    unsigned short* wb  = (unsigned short*)ws;               // 720896 bf16 weights
    unsigned short* W5b = wb + 458752;
    unsigned short* lin = (unsigned short*)(ws + 1441792);   // 9 x 32768x256 bf16
    unsigned short* Q1 = lin + 0ull * 8388608;
    unsigned short* Q2 = lin + 1ull * 8388608;
    unsigned short* Q3 = lin + 2ull * 8388608;
    unsigned short* Q4 = lin + 3ull * 8388608;
    unsigned short* K3 = lin + 4ull * 8388608;
    unsigned short* V1 = lin + 5ull * 8388608;
    unsigned short* V2 = lin + 6ull * 8388608;
    unsigned short* V3 = lin + 7ull * 8388608;
    unsigned short* V4 = lin + 8ull * 8388608;
    unsigned short* partial2 = (unsigned short*)(ws + 152436736);  // 4*32*65536 bf16
    float* dinvP   = (float*)(ws + 185991168);               // 4*65536 f32 (permuted)
    unsigned short* ob4 = (unsigned short*)(ws + 152436736); // o4 bf16, overlaps dead partial2

    float* outf = (float*)d_out;   // planes: o1(0) o2(1) o5(2) o3(3)
    float* o5p = outf + 2ull * 8388608;
    unsigned short* Xb = (unsigned short*)d_out;  // q1..q3 bf16 scratch in o1/o2 planes

    dim3 blk(256);

    hipLaunchKernelGGL(k_convert_w, dim3(2816), blk, 0, stream,
                       WQ, WV, WQ3, WK3, WV3, WQ4, WV4, W5, wb);
    hipLaunchKernelGGL(k_convert_x, dim3(12288), blk, 0, stream,
                       q1, q2, q3, Xb);

    hipLaunchKernelGGL(k_linear, dim3(2560), dim3(512), 0, stream,
                       Xb, adj, wb,
                       bQ, bV, bQ3, bK3, bV3, bQ4, bV4, lin);

    hipLaunchKernelGGL(k_denom, dim3(4, 32, 4), blk, 0, stream,
                       Q1, Q2, Q3, Q4, K3, partial2);
    hipLaunchKernelGGL(k_reduce, dim3(256, 4), blk, 0, stream, partial2, dinvP);

    hipLaunchKernelGGL(k_attn, dim3(4096), blk, 0, stream,
                       Q1, Q2, Q3, Q4, K3, V1, V2, V3, V4, dinvP,
                       outf, ob4);

    hipLaunchKernelGGL(k_final, dim3(256), dim3(512), 0, stream,
                       outf, outf + 8388608ull, outf + 3ull * 8388608, ob4,
                       W5b, b5, o5p);
}